// Round 3
// baseline (191.985 us; speedup 1.0000x reference)
//
#include <hip/hip_runtime.h>

#define MARGIN 0.1f
#define NBLOCKS 4096
#define BLOCK 256

// One 32-lane group per 8 consecutive rows (G=128 -> 4 floats/lane via float4).
// All 8 row-loads + 2 label loads are issued before any compute: max MLP.
// 4096 blocks x 8 groups x 8 rows = 262144 = N exactly (single pass).
__global__ __launch_bounds__(BLOCK) void margin_partials_kernel(
    const float* __restrict__ inputs,
    const int*   __restrict__ labels,
    float*       __restrict__ partials,
    int N)
{
    const int G = 128;
    const int ROWS = 8;
    const int tid    = blockIdx.x * blockDim.x + threadIdx.x;
    const int group  = tid >> 5;
    const int lane32 = tid & 31;

    float partial = 0.0f;
    const int base = group * ROWS;

    if (base < N) {
        // Issue every load up front: 8 independent float4 + 2 int4.
        const int4 labA = *(const int4*)(labels + base);
        const int4 labB = *(const int4*)(labels + base + 4);

        float4 v[ROWS];
        #pragma unroll
        for (int r = 0; r < ROWS; ++r)
            v[r] = ((const float4*)(inputs + (size_t)(base + r) * G))[lane32];

        const int lab[ROWS] = { labA.x, labA.y, labA.z, labA.w,
                                labB.x, labB.y, labB.z, labB.w };

        #pragma unroll
        for (int r = 0; r < ROWS; ++r) {
            const int lbl = lab[r];        // group-uniform: no divergence
            float cand;
            switch (lbl & 3) {
                case 0:  cand = v[r].x; break;
                case 1:  cand = v[r].y; break;
                case 2:  cand = v[r].z; break;
                default: cand = v[r].w; break;
            }
            const float mc = MARGIN - __shfl(cand, lbl >> 2, 32);
            // j==label term contributes MARGIN (to ~1ulp); removed in kernel 2.
            partial += fmaxf(mc + v[r].x, 0.0f) + fmaxf(mc + v[r].y, 0.0f)
                     + fmaxf(mc + v[r].z, 0.0f) + fmaxf(mc + v[r].w, 0.0f);
        }
    }

    // Reduce across the full 64-lane wave.
    #pragma unroll
    for (int off = 32; off > 0; off >>= 1)
        partial += __shfl_down(partial, off, 64);

    __shared__ float wsum[BLOCK / 64];
    const int wave = threadIdx.x >> 6;
    if ((threadIdx.x & 63) == 0) wsum[wave] = partial;
    __syncthreads();

    if (threadIdx.x == 0) {
        float bs = 0.0f;
        #pragma unroll
        for (int w = 0; w < BLOCK / 64; ++w) bs += wsum[w];
        partials[blockIdx.x] = bs;   // plain store: overwrites 0xAA poison
    }
}

// Kernel 2: reduce NBLOCKS partials, subtract the j==label contribution
// (MARGIN per row), scale, store the scalar.
__global__ __launch_bounds__(BLOCK) void margin_finalize_kernel(
    const float* __restrict__ partials,
    float*       __restrict__ out,
    int N, float inv_denom)
{
    float s = 0.0f;
    for (int i = threadIdx.x; i < NBLOCKS; i += BLOCK)
        s += partials[i];

    #pragma unroll
    for (int off = 32; off > 0; off >>= 1)
        s += __shfl_down(s, off, 64);

    __shared__ float wsum[BLOCK / 64];
    const int wave = threadIdx.x >> 6;
    if ((threadIdx.x & 63) == 0) wsum[wave] = s;
    __syncthreads();

    if (threadIdx.x == 0) {
        float total = 0.0f;
        #pragma unroll
        for (int w = 0; w < BLOCK / 64; ++w) total += wsum[w];
        total -= MARGIN * (float)N;          // remove j==label terms
        *out = total * inv_denom;
    }
}

extern "C" void kernel_launch(void* const* d_in, const int* in_sizes, int n_in,
                              void* d_out, int out_size, void* d_ws, size_t ws_size,
                              hipStream_t stream) {
    const float* inputs = (const float*)d_in[0];
    const int*   labels = (const int*)d_in[1];
    float*       out    = (float*)d_out;
    float*       partials = (float*)d_ws;    // NBLOCKS floats of scratch

    const int N = in_sizes[1];               // 262144 rows
    const int G = 128;
    const float inv_denom = 1.0f / ((float)N * (float)(G - 1));

    margin_partials_kernel<<<NBLOCKS, BLOCK, 0, stream>>>(inputs, labels, partials, N);
    margin_finalize_kernel<<<1, BLOCK, 0, stream>>>(partials, out, N, inv_denom);
}

// Round 4
// 190.113 us; speedup vs baseline: 1.0098x; 1.0098x over previous
//
#include <hip/hip_runtime.h>

#define MARGIN 0.1f
#define NBLOCKS 2048
#define BLOCK 256

// One 32-lane group per 16 consecutive rows (G=128 -> 4 floats/lane via float4).
// All 16 row-loads + 4 label loads issued up-front: 16 vmem ops in flight per
// lane, targeting the L3-resident-input regime (inputs = 128 MiB < 256 MiB L3).
// 2048 blocks x 8 groups x 16 rows = 262144 = N exactly (single pass).
__global__ __launch_bounds__(BLOCK) void margin_partials_kernel(
    const float* __restrict__ inputs,
    const int*   __restrict__ labels,
    float*       __restrict__ partials,
    int N)
{
    const int G = 128;
    const int ROWS = 16;
    const int tid    = blockIdx.x * blockDim.x + threadIdx.x;
    const int group  = tid >> 5;
    const int lane32 = tid & 31;

    float partial = 0.0f;
    const int base = group * ROWS;

    if (base < N) {
        const int4 labA = *(const int4*)(labels + base);
        const int4 labB = *(const int4*)(labels + base + 4);
        const int4 labC = *(const int4*)(labels + base + 8);
        const int4 labD = *(const int4*)(labels + base + 12);

        float4 v[ROWS];
        #pragma unroll
        for (int r = 0; r < ROWS; ++r)
            v[r] = ((const float4*)(inputs + (size_t)(base + r) * G))[lane32];

        const int lab[ROWS] = { labA.x, labA.y, labA.z, labA.w,
                                labB.x, labB.y, labB.z, labB.w,
                                labC.x, labC.y, labC.z, labC.w,
                                labD.x, labD.y, labD.z, labD.w };

        #pragma unroll
        for (int r = 0; r < ROWS; ++r) {
            const int lbl = lab[r];        // group-uniform: no divergence
            float cand;
            switch (lbl & 3) {
                case 0:  cand = v[r].x; break;
                case 1:  cand = v[r].y; break;
                case 2:  cand = v[r].z; break;
                default: cand = v[r].w; break;
            }
            const float mc = MARGIN - __shfl(cand, lbl >> 2, 32);
            // j==label term contributes MARGIN (to ~1ulp); removed in kernel 2.
            partial += fmaxf(mc + v[r].x, 0.0f) + fmaxf(mc + v[r].y, 0.0f)
                     + fmaxf(mc + v[r].z, 0.0f) + fmaxf(mc + v[r].w, 0.0f);
        }
    }

    // Reduce across the full 64-lane wave.
    #pragma unroll
    for (int off = 32; off > 0; off >>= 1)
        partial += __shfl_down(partial, off, 64);

    __shared__ float wsum[BLOCK / 64];
    const int wave = threadIdx.x >> 6;
    if ((threadIdx.x & 63) == 0) wsum[wave] = partial;
    __syncthreads();

    if (threadIdx.x == 0) {
        float bs = 0.0f;
        #pragma unroll
        for (int w = 0; w < BLOCK / 64; ++w) bs += wsum[w];
        partials[blockIdx.x] = bs;   // plain store: overwrites 0xAA poison
    }
}

// Kernel 2: reduce NBLOCKS partials, subtract the j==label contribution
// (MARGIN per row), scale, store the scalar.
__global__ __launch_bounds__(BLOCK) void margin_finalize_kernel(
    const float* __restrict__ partials,
    float*       __restrict__ out,
    int N, float inv_denom)
{
    float s = 0.0f;
    for (int i = threadIdx.x; i < NBLOCKS; i += BLOCK)
        s += partials[i];

    #pragma unroll
    for (int off = 32; off > 0; off >>= 1)
        s += __shfl_down(s, off, 64);

    __shared__ float wsum[BLOCK / 64];
    const int wave = threadIdx.x >> 6;
    if ((threadIdx.x & 63) == 0) wsum[wave] = s;
    __syncthreads();

    if (threadIdx.x == 0) {
        float total = 0.0f;
        #pragma unroll
        for (int w = 0; w < BLOCK / 64; ++w) total += wsum[w];
        total -= MARGIN * (float)N;          // remove j==label terms
        *out = total * inv_denom;
    }
}

extern "C" void kernel_launch(void* const* d_in, const int* in_sizes, int n_in,
                              void* d_out, int out_size, void* d_ws, size_t ws_size,
                              hipStream_t stream) {
    const float* inputs = (const float*)d_in[0];
    const int*   labels = (const int*)d_in[1];
    float*       out    = (float*)d_out;
    float*       partials = (float*)d_ws;    // NBLOCKS floats of scratch

    const int N = in_sizes[1];               // 262144 rows
    const int G = 128;
    const float inv_denom = 1.0f / ((float)N * (float)(G - 1));

    margin_partials_kernel<<<NBLOCKS, BLOCK, 0, stream>>>(inputs, labels, partials, N);
    margin_finalize_kernel<<<1, BLOCK, 0, stream>>>(partials, out, N, inv_denom);
}